// Round 4
// baseline (120.884 us; speedup 1.0000x reference)
//
#include <hip/hip_runtime.h>
#include <hip/hip_fp16.h>

// term = log(sigmoid(x) + 1e-8) ~= -log(1 + min(exp(-x), 1e8))
// 1e8 clamp implements the +1e-8 floor (-log(1+1e8) = -18.42). Band error
// x in [-20,-16]: <=0.69/term, ~0.3% population -> ~2e3 total << 9.6e4 thr.
// 4-way log pairing: prod (1+t_k) <= 1e32 < fp32 max. 10 trans / 8 terms.

#define NG_SHIFT 11
#define NG 2048          // nodes per group -> 32KB fp16 subtable
#define MAX_B 2500       // max buckets supported by K1 LDS histograms
#define CAP 1792         // records per bucket (mean 1333 + 12.6 sigma)
#define OVF_CAP 65536
#define K1_TPB 512
#define K1_CHUNK 8192    // edges per K1 block
#define K2_TPB 512
#define OVF_BLOCKS 8

__device__ __forceinline__ float edge_term(uint4 A, uint4 B) {
    const __half2* ah = (const __half2*)&A;
    const __half2* bh = (const __half2*)&B;
    float t[8];
#pragma unroll
    for (int k = 0; k < 4; ++k) {
        __half2 xh = __hmul2(ah[k], bh[k]);      // inf-safe: limits correct
        float2 xf = __half22float2(xh);
        t[2 * k]     = fminf(__expf(-xf.x), 1.0e8f);
        t[2 * k + 1] = fminf(__expf(-xf.y), 1.0e8f);
    }
    float p0 = 1.0f + t[0];
    p0 = __builtin_fmaf(p0, t[1], p0);
    p0 = __builtin_fmaf(p0, t[2], p0);
    p0 = __builtin_fmaf(p0, t[3], p0);
    float p1 = 1.0f + t[4];
    p1 = __builtin_fmaf(p1, t[5], p1);
    p1 = __builtin_fmaf(p1, t[6], p1);
    p1 = __builtin_fmaf(p1, t[7], p1);
    return __logf(p0) + __logf(p1);              // positive; negate at end
}

// ---------------- K0: c[n][0..7] fp16 packed (16B/node); last block zeroes
// out + bucket counters + misc + partials.
__global__ void compute_c_h8(const float* __restrict__ mu,
                             const float* __restrict__ ls,
                             const float* __restrict__ eps,
                             __half2* __restrict__ c, int N,
                             float* __restrict__ out, int out_size,
                             unsigned int* __restrict__ gcnt, int B,
                             unsigned int* __restrict__ misc,
                             float* __restrict__ partials) {
    if (blockIdx.x == gridDim.x - 1) {
        for (int i = threadIdx.x; i < out_size; i += blockDim.x) out[i] = 0.0f;
        if (gcnt) {
            for (int i = threadIdx.x; i < B; i += blockDim.x) gcnt[i] = 0u;
            if (threadIdx.x < 2) misc[threadIdx.x] = 0u;      // ovfcnt, donecnt
            for (int i = threadIdx.x; i < 1024; i += blockDim.x) partials[i] = 0.0f;
        }
        return;
    }
    int n = blockIdx.x * blockDim.x + threadIdx.x;
    if (n >= N) return;
    float m  = mu[n];
    float sg = __expf(ls[n]);
    float v[8];
#pragma unroll
    for (int s = 0; s < 8; ++s) v[s] = m + sg * eps[(size_t)s * N + n];
    __half2* dst = c + (size_t)n * 4;
#pragma unroll
    for (int s = 0; s < 4; ++s) dst[s] = __floats2half2_rn(v[2 * s], v[2 * s + 1]);
}

// ---------------- K1: bucket + scatter. Per block: LDS histogram of its edge
// chunk, one global-atomic reservation per touched bucket, then scatter packed
// (li | lj<<16) records. Overflowing edges go to a global overflow list.
__global__ void __launch_bounds__(K1_TPB)
bucket_scatter(const int2* __restrict__ edges, long long E, int G, int B,
               unsigned int* __restrict__ recs,
               unsigned int* __restrict__ gcnt,
               int2* __restrict__ ovf,
               unsigned int* __restrict__ misc) {
    __shared__ unsigned int hist[MAX_B];
    __shared__ unsigned int base[MAX_B];
    long long start = (long long)blockIdx.x * K1_CHUNK;

    for (int i = threadIdx.x; i < B; i += K1_TPB) hist[i] = 0u;
    __syncthreads();
#pragma unroll
    for (int k = 0; k < K1_CHUNK / K1_TPB; ++k) {
        long long idx = start + (long long)k * K1_TPB + threadIdx.x;
        if (idx < E) {
            int2 e = edges[idx];
            int b = (e.x >> NG_SHIFT) * G + (e.y >> NG_SHIFT);
            atomicAdd(&hist[b], 1u);
        }
    }
    __syncthreads();
    for (int i = threadIdx.x; i < B; i += K1_TPB) {
        unsigned int h = hist[i];
        base[i] = h ? atomicAdd(&gcnt[i], h) : 0u;
        hist[i] = 0u;                                  // reuse as rank counter
    }
    __syncthreads();
#pragma unroll
    for (int k = 0; k < K1_CHUNK / K1_TPB; ++k) {
        long long idx = start + (long long)k * K1_TPB + threadIdx.x;
        if (idx < E) {
            int2 e = edges[idx];                       // chunk is L2-hot now
            int b = (e.x >> NG_SHIFT) * G + (e.y >> NG_SHIFT);
            unsigned int rank = atomicAdd(&hist[b], 1u);
            unsigned int pos  = base[b] + rank;
            if (pos < CAP) {
                recs[(size_t)b * CAP + pos] =
                    (unsigned int)(e.x & (NG - 1)) | ((unsigned int)(e.y & (NG - 1)) << 16);
            } else {
                unsigned int op = atomicAdd(&misc[0], 1u);
                if (op < OVF_CAP) ovf[op] = e;
            }
        }
    }
}

// ---------------- K2: per-bucket compute with both subtables LDS-resident.
// Blocks >= B drain the overflow list via direct global gathers.
// Last block (donecnt protocol) reduces the 1024 partials into out[0].
__global__ void __launch_bounds__(K2_TPB)
bucket_compute(const uint4* __restrict__ c,
               const unsigned int* __restrict__ recs,
               const unsigned int* __restrict__ gcnt,
               const int2* __restrict__ ovf,
               unsigned int* __restrict__ misc,
               float* __restrict__ partials,
               float* __restrict__ out,
               int G, int B, int gridTotal, float neg_inv_s) {
    __shared__ uint4 SA[NG];
    __shared__ uint4 SB[NG];
    float acc = 0.0f;
    int b = blockIdx.x;

    if (b < B) {
        unsigned int nb = gcnt[b];                     // block-uniform
        if (nb > CAP) nb = CAP;
        if (nb) {
            int gi = b / G, gj = b - gi * G;
            const uint4* Ai = c + (size_t)gi * NG;
            const uint4* Bj = c + (size_t)gj * NG;
            for (int t = threadIdx.x; t < NG; t += K2_TPB) { SA[t] = Ai[t]; SB[t] = Bj[t]; }
            __syncthreads();
            const unsigned int* r = recs + (size_t)b * CAP;
            for (unsigned int k = threadIdx.x; k < nb; k += K2_TPB) {
                unsigned int rec = r[k];
                uint4 a = SA[rec & 0xFFFFu];
                uint4 v = SB[rec >> 16];
                acc += edge_term(a, v);
            }
        }
    } else {
        unsigned int no = misc[0];
        if (no > OVF_CAP) no = OVF_CAP;
        for (unsigned int k = (unsigned int)(b - B) * K2_TPB + threadIdx.x;
             k < no; k += OVF_BLOCKS * K2_TPB) {
            int2 e = ovf[k];
            acc += edge_term(c[e.x], c[e.y]);          // entry index == node id
        }
    }

    // wave reduce -> spread partial atomics over 1024 slots
#pragma unroll
    for (int off = 32; off > 0; off >>= 1) acc += __shfl_down(acc, off, 64);
    int wid = threadIdx.x >> 6;
    if ((threadIdx.x & 63) == 0)
        atomicAdd(&partials[((unsigned int)blockIdx.x * 8u + (unsigned int)wid) & 1023u], acc);

    // completion protocol: last block reduces partials -> out
    __syncthreads();                                    // drains this block's atomics
    int* flag = (int*)SA;                               // SA/SB free now
    if (threadIdx.x == 0) {
        __threadfence();
        unsigned int d = atomicAdd(&misc[1], 1u);
        flag[0] = (d == (unsigned int)(gridTotal - 1)) ? 1 : 0;
    }
    __syncthreads();
    if (flag[0]) {
        float s = atomicAdd(&partials[threadIdx.x], 0.0f)
                + atomicAdd(&partials[threadIdx.x + 512], 0.0f);
#pragma unroll
        for (int off = 32; off > 0; off >>= 1) s += __shfl_down(s, off, 64);
        float* fs = (float*)SB;
        if ((threadIdx.x & 63) == 0) fs[wid] = s;
        __syncthreads();
        if (threadIdx.x == 0) {
            float tot = 0.0f;
            for (int w = 0; w < K2_TPB / 64; ++w) tot += fs[w];
            out[0] = tot * neg_inv_s;
        }
    }
}

// ---------------- fallback: direct-gather path (R3), int32 edges
__global__ void __launch_bounds__(256, 8)
edge_loglik_direct(const int4* __restrict__ ep, const uint4* __restrict__ c,
                   float* __restrict__ out, long long E, float inv_s) {
    long long tid    = (long long)blockIdx.x * blockDim.x + threadIdx.x;
    long long stride = (long long)gridDim.x * blockDim.x;
    float acc = 0.0f;
    long long P = E >> 1;
    for (long long q = tid; q < P; q += stride) {
        int4 ee = ep[q];
        acc += edge_term(c[ee.x], c[ee.y]) + edge_term(c[ee.z], c[ee.w]);
    }
    if ((E & 1) && tid == 0) {
        const int2* el = (const int2*)ep;
        int2 ij = el[E - 1];
        acc += edge_term(c[ij.x], c[ij.y]);
    }
#pragma unroll
    for (int off = 32; off > 0; off >>= 1) acc += __shfl_down(acc, off, 64);
    __shared__ float wsum[8];
    int lane = threadIdx.x & 63, wid = threadIdx.x >> 6;
    if (lane == 0) wsum[wid] = acc;
    __syncthreads();
    if (threadIdx.x == 0) {
        float s = 0.0f;
        for (int w = 0; w < (int)(blockDim.x >> 6); ++w) s += wsum[w];
        atomicAdd(out, -s * inv_s);
    }
}

// generic-S fallback
__global__ void compute_c_gen(const float* __restrict__ mu, const float* __restrict__ ls,
                              const float* __restrict__ eps, __half* __restrict__ c,
                              int N, int S, float* __restrict__ out, int out_size) {
    if (blockIdx.x == gridDim.x - 1) {
        for (int i = threadIdx.x; i < out_size; i += blockDim.x) out[i] = 0.0f;
        return;
    }
    int n = blockIdx.x * blockDim.x + threadIdx.x;
    if (n >= N) return;
    float m = mu[n], sg = __expf(ls[n]);
    for (int s = 0; s < S; ++s) c[(size_t)n * S + s] = __float2half(m + sg * eps[(size_t)s * N + n]);
}
__global__ void edge_loglik_gen(const int* __restrict__ ed, const __half* __restrict__ c,
                                float* __restrict__ out, long long E, int S, float inv_s) {
    long long tid = (long long)blockIdx.x * blockDim.x + threadIdx.x;
    long long stride = (long long)gridDim.x * blockDim.x;
    float acc = 0.0f;
    for (long long e = tid; e < E; e += stride) {
        long long i = ed[2 * e], j = ed[2 * e + 1];
        for (int s = 0; s < S; ++s) {
            float x = __half2float(c[i * S + s]) * __half2float(c[j * S + s]);
            acc += __logf(1.0f + fminf(__expf(-x), 1.0e8f));
        }
    }
#pragma unroll
    for (int off = 32; off > 0; off >>= 1) acc += __shfl_down(acc, off, 64);
    __shared__ float wsum[8];
    int lane = threadIdx.x & 63, wid = threadIdx.x >> 6;
    if (lane == 0) wsum[wid] = acc;
    __syncthreads();
    if (threadIdx.x == 0) {
        float s = 0.0f;
        for (int w = 0; w < (int)(blockDim.x >> 6); ++w) s += wsum[w];
        atomicAdd(out, -s * inv_s);
    }
}

extern "C" void kernel_launch(void* const* d_in, const int* in_sizes, int n_in,
                              void* d_out, int out_size, void* d_ws, size_t ws_size,
                              hipStream_t stream) {
    const float* mu  = (const float*)d_in[0];
    const float* ls  = (const float*)d_in[1];
    const float* eps = (const float*)d_in[2];
    const int* edges = (const int*)d_in[3];    // int32 pairs (proven via FETCH_SIZE R1)

    int       N = in_sizes[0];
    int       S = in_sizes[2] / N;             // 8
    long long E = (long long)in_sizes[3] / 2;  // 3.2M

    int    G    = (N + NG - 1) >> NG_SHIFT;    // 49
    int    B    = G * G;                       // 2401
    size_t NTAB = (size_t)G * NG;

    char* p = (char*)d_ws;
    __half* c = (__half*)p;
    size_t sz_c    = NTAB * 16;
    unsigned int* recs = (unsigned int*)(p + sz_c);
    size_t sz_recs = (size_t)B * CAP * 4;
    int2* ovf = (int2*)(p + sz_c + sz_recs);
    size_t sz_ovf  = (size_t)OVF_CAP * 8;
    unsigned int* gcnt = (unsigned int*)(p + sz_c + sz_recs + sz_ovf);
    size_t sz_gcnt = (((size_t)B * 4) + 255) & ~(size_t)255;
    unsigned int* misc = (unsigned int*)((char*)gcnt + sz_gcnt);
    float* partials = (float*)(misc + 16);
    size_t need = sz_c + sz_recs + sz_ovf + sz_gcnt + 64 + 1024 * 4 + 256;

    float* out = (float*)d_out;
    int cblocks = (N + 255) / 256 + 1;

    if (S == 8 && B <= MAX_B && ws_size >= need && E > 0) {
        compute_c_h8<<<cblocks, 256, 0, stream>>>(mu, ls, eps, (__half2*)c, N,
                                                  out, out_size, gcnt, B, misc, partials);
        int k1b = (int)((E + K1_CHUNK - 1) / K1_CHUNK);
        bucket_scatter<<<k1b, K1_TPB, 0, stream>>>((const int2*)edges, E, G, B,
                                                   recs, gcnt, ovf, misc);
        int k2b = B + OVF_BLOCKS;
        bucket_compute<<<k2b, K2_TPB, 0, stream>>>((const uint4*)c, recs, gcnt, ovf,
                                                   misc, partials, out, G, B, k2b,
                                                   -1.0f / (float)S);
    } else if (S == 8 && ws_size >= sz_c) {
        compute_c_h8<<<cblocks, 256, 0, stream>>>(mu, ls, eps, (__half2*)c, N,
                                                  out, out_size, nullptr, 0, nullptr, nullptr);
        edge_loglik_direct<<<2048, 256, 0, stream>>>((const int4*)edges, (const uint4*)c,
                                                     out, E, 1.0f / (float)S);
    } else {
        compute_c_gen<<<cblocks, 256, 0, stream>>>(mu, ls, eps, c, N, S, out, out_size);
        edge_loglik_gen<<<2048, 256, 0, stream>>>(edges, c, out, E, S, 1.0f / (float)S);
    }
}

// Round 5
// 83.735 us; speedup vs baseline: 1.4436x; 1.4436x over previous
//
#include <hip/hip_runtime.h>
#include <hip/hip_fp16.h>

// term = log(sigmoid(x) + 1e-8) ~= -log(1 + min(exp(-x), 1e8))
// 1e8 clamp implements the +1e-8 floor (-log(1+1e8) = -18.42). Band error
// x in [-20,-16]: <=0.69/term, ~0.3% population -> ~2e3 total << 9.6e4 thr.
// 4-way log pairing: prod (1+t_k) <= 1e32 < fp32 max. 10 trans / 8 terms.
// Numerics identical to R3 (passed with absmax 0.0).

typedef unsigned int u32x4 __attribute__((ext_vector_type(4)));

__device__ __forceinline__ float edge_term(u32x4 A, u32x4 B) {
    float t[8];
#pragma unroll
    for (int k = 0; k < 4; ++k) {
        __half2 a = __builtin_bit_cast(__half2, A[k]);
        __half2 b = __builtin_bit_cast(__half2, B[k]);
        __half2 xh = __hmul2(a, b);          // inf-safe: limits correct
        float2 xf = __half22float2(xh);
        t[2 * k]     = fminf(__expf(-xf.x), 1.0e8f);
        t[2 * k + 1] = fminf(__expf(-xf.y), 1.0e8f);
    }
    float p0 = 1.0f + t[0];
    p0 = __builtin_fmaf(p0, t[1], p0);
    p0 = __builtin_fmaf(p0, t[2], p0);
    p0 = __builtin_fmaf(p0, t[3], p0);
    float p1 = 1.0f + t[4];
    p1 = __builtin_fmaf(p1, t[5], p1);
    p1 = __builtin_fmaf(p1, t[6], p1);
    p1 = __builtin_fmaf(p1, t[7], p1);
    return __logf(p0) + __logf(p1);          // positive; negated at the end
}

// ---------------- K0: c[n][0..7] fp16 packed (16 B/node); last block zeroes out
__global__ void compute_c_h8(const float* __restrict__ mu,
                             const float* __restrict__ ls,
                             const float* __restrict__ eps,
                             __half2* __restrict__ c, int N,
                             float* __restrict__ out, int out_size) {
    if (blockIdx.x == gridDim.x - 1) {
        for (int i = threadIdx.x; i < out_size; i += blockDim.x) out[i] = 0.0f;
        return;
    }
    int n = blockIdx.x * blockDim.x + threadIdx.x;
    if (n >= N) return;
    float m  = mu[n];
    float sg = __expf(ls[n]);
    float v[8];
#pragma unroll
    for (int s = 0; s < 8; ++s) v[s] = m + sg * eps[(size_t)s * N + n];
    __half2* dst = c + (size_t)n * 4;
#pragma unroll
    for (int s = 0; s < 4; ++s) dst[s] = __floats2half2_rn(v[2 * s], v[2 * s + 1]);
}

// ---------------- edge kernel over int4-pair range [q0, q0+qn).
// NT=true: table gathers use nontemporal (L1 no-allocate) loads.
// Within-probe A/B: two dispatches, identical except NT, each half the edges.
template <bool NT>
__global__ void __launch_bounds__(256, 8)
edge_loglik_half(const int4* __restrict__ ep, const u32x4* __restrict__ c,
                 float* __restrict__ out, long long q0, long long qn,
                 long long E, int handle_tail, float neg_inv_s) {
    long long tid    = (long long)blockIdx.x * blockDim.x + threadIdx.x;
    long long stride = (long long)gridDim.x * blockDim.x;
    long long qend   = q0 + qn;
    float acc = 0.0f;

    for (long long q = q0 + tid; q < qend; q += 2 * stride) {
        long long q1 = q + stride;
        bool has1 = q1 < qend;
        int4 e0 = ep[q];
        int4 e1 = has1 ? ep[q1] : e0;
        u32x4 a0, b0, d0, f0, a1, b1, d1, f1;
        if constexpr (NT) {
            a0 = __builtin_nontemporal_load(c + e0.x);
            b0 = __builtin_nontemporal_load(c + e0.y);
            d0 = __builtin_nontemporal_load(c + e0.z);
            f0 = __builtin_nontemporal_load(c + e0.w);
            a1 = __builtin_nontemporal_load(c + e1.x);
            b1 = __builtin_nontemporal_load(c + e1.y);
            d1 = __builtin_nontemporal_load(c + e1.z);
            f1 = __builtin_nontemporal_load(c + e1.w);
        } else {
            a0 = c[e0.x]; b0 = c[e0.y]; d0 = c[e0.z]; f0 = c[e0.w];
            a1 = c[e1.x]; b1 = c[e1.y]; d1 = c[e1.z]; f1 = c[e1.w];
        }
        float s = edge_term(a0, b0) + edge_term(d0, f0);
        if (has1) s += edge_term(a1, b1) + edge_term(d1, f1);
        acc += s;
    }
    if (handle_tail && (E & 1) && tid == 0) {
        const int2* el = (const int2*)ep;
        int2 ij = el[E - 1];
        acc += edge_term(c[ij.x], c[ij.y]);
    }

    // wave (64-lane) reduction -> one atomic per block
#pragma unroll
    for (int off = 32; off > 0; off >>= 1) acc += __shfl_down(acc, off, 64);
    __shared__ float wsum[4];
    int lane = threadIdx.x & 63;
    int wid  = threadIdx.x >> 6;
    if (lane == 0) wsum[wid] = acc;
    __syncthreads();
    if (threadIdx.x == 0) {
        float s = 0.0f;
        for (int w = 0; w < (int)(blockDim.x >> 6); ++w) s += wsum[w];
        atomicAdd(out, s * neg_inv_s);
    }
}

// ---------------- generic-S fallback (harness uses S=8; kept for safety)
__global__ void compute_c_gen(const float* __restrict__ mu, const float* __restrict__ ls,
                              const float* __restrict__ eps, __half* __restrict__ c,
                              int N, int S, float* __restrict__ out, int out_size) {
    if (blockIdx.x == gridDim.x - 1) {
        for (int i = threadIdx.x; i < out_size; i += blockDim.x) out[i] = 0.0f;
        return;
    }
    int n = blockIdx.x * blockDim.x + threadIdx.x;
    if (n >= N) return;
    float m = mu[n], sg = __expf(ls[n]);
    for (int s = 0; s < S; ++s) c[(size_t)n * S + s] = __float2half(m + sg * eps[(size_t)s * N + n]);
}
__global__ void edge_loglik_gen(const int* __restrict__ ed, const __half* __restrict__ c,
                                float* __restrict__ out, long long E, int S, float neg_inv_s) {
    long long tid = (long long)blockIdx.x * blockDim.x + threadIdx.x;
    long long stride = (long long)gridDim.x * blockDim.x;
    float acc = 0.0f;
    for (long long e = tid; e < E; e += stride) {
        long long i = ed[2 * e], j = ed[2 * e + 1];
        for (int s = 0; s < S; ++s) {
            float x = __half2float(c[i * S + s]) * __half2float(c[j * S + s]);
            acc += __logf(1.0f + fminf(__expf(-x), 1.0e8f));
        }
    }
#pragma unroll
    for (int off = 32; off > 0; off >>= 1) acc += __shfl_down(acc, off, 64);
    __shared__ float wsum[8];
    int lane = threadIdx.x & 63, wid = threadIdx.x >> 6;
    if (lane == 0) wsum[wid] = acc;
    __syncthreads();
    if (threadIdx.x == 0) {
        float s = 0.0f;
        for (int w = 0; w < (int)(blockDim.x >> 6); ++w) s += wsum[w];
        atomicAdd(out, s * neg_inv_s);
    }
}

extern "C" void kernel_launch(void* const* d_in, const int* in_sizes, int n_in,
                              void* d_out, int out_size, void* d_ws, size_t ws_size,
                              hipStream_t stream) {
    const float* mu  = (const float*)d_in[0];
    const float* ls  = (const float*)d_in[1];
    const float* eps = (const float*)d_in[2];
    const int* edges = (const int*)d_in[3];    // int32 pairs (confirmed: R4 passed assuming int32)

    int       N = in_sizes[0];
    int       S = in_sizes[2] / N;             // 8
    long long E = (long long)in_sizes[3] / 2;  // 3.2M

    __half* c  = (__half*)d_ws;
    float* out = (float*)d_out;
    size_t sz_c = (size_t)N * S * sizeof(__half);
    float neg_inv_s = -1.0f / (float)S;

    int cblocks = (N + 255) / 256 + 1;         // +1 block zeroes d_out

    if (S == 8 && ws_size >= sz_c) {
        compute_c_h8<<<cblocks, 256, 0, stream>>>(mu, ls, eps, (__half2*)c, N, out, out_size);
        long long P  = E >> 1;                 // int4 edge-pairs
        long long QA = P >> 1;
        long long QB = P - QA;
        // A/B: identical kernels, NT gathers vs plain, half the edges each
        edge_loglik_half<true ><<<2048, 256, 0, stream>>>((const int4*)edges, (const u32x4*)c,
                                                          out, 0,  QA, E, 0, neg_inv_s);
        edge_loglik_half<false><<<2048, 256, 0, stream>>>((const int4*)edges, (const u32x4*)c,
                                                          out, QA, QB, E, 1, neg_inv_s);
    } else {
        compute_c_gen<<<cblocks, 256, 0, stream>>>(mu, ls, eps, c, N, S, out, out_size);
        edge_loglik_gen<<<2048, 256, 0, stream>>>(edges, c, out, E, S, neg_inv_s);
    }
}

// Round 7
// 46.933 us; speedup vs baseline: 2.5757x; 1.7842x over previous
//
#include <hip/hip_runtime.h>
#include <hip/hip_fp16.h>

// term = log(sigmoid(x) + 1e-8) ~= -log(1 + min(exp(-x), 1e8))
// 1e8 clamp implements the +1e-8 floor (-log(1+1e8) = -18.42). Band error
// x in [-20,-16]: <=0.69/term, ~0.3% population -> ~2e3 total << 9.6e4 thr.
// 4-way log pairing: prod (1+t_k) <= 1e32 < fp32 max. 10 trans / 8 terms.
// Numerics identical to R3/R5 (both passed with absmax 0.0).
//
// R7 = R6 with the compile fix: __builtin_nontemporal_load needs an
// ext_vector_type pointer, not HIP's int4. Single variable vs R3: the
// zero-reuse 25.6 MB edge stream is loaded nontemporal (L2 no-allocate)
// so it stops evicting the 1.6 MB c-table from each XCD's 4 MiB L2;
// table gathers stay normally cached -> L2 hits.

typedef unsigned int u32x4 __attribute__((ext_vector_type(4)));
typedef int          i32x4 __attribute__((ext_vector_type(4)));

__device__ __forceinline__ float edge_term(u32x4 A, u32x4 B) {
    float t[8];
#pragma unroll
    for (int k = 0; k < 4; ++k) {
        __half2 a = __builtin_bit_cast(__half2, A[k]);
        __half2 b = __builtin_bit_cast(__half2, B[k]);
        __half2 xh = __hmul2(a, b);          // inf-safe: limits correct
        float2 xf = __half22float2(xh);
        t[2 * k]     = fminf(__expf(-xf.x), 1.0e8f);
        t[2 * k + 1] = fminf(__expf(-xf.y), 1.0e8f);
    }
    float p0 = 1.0f + t[0];
    p0 = __builtin_fmaf(p0, t[1], p0);
    p0 = __builtin_fmaf(p0, t[2], p0);
    p0 = __builtin_fmaf(p0, t[3], p0);
    float p1 = 1.0f + t[4];
    p1 = __builtin_fmaf(p1, t[5], p1);
    p1 = __builtin_fmaf(p1, t[6], p1);
    p1 = __builtin_fmaf(p1, t[7], p1);
    return __logf(p0) + __logf(p1);          // positive; negated at the end
}

// ---------------- K0: c[n][0..7] fp16 packed (16 B/node); last block zeroes out
__global__ void compute_c_h8(const float* __restrict__ mu,
                             const float* __restrict__ ls,
                             const float* __restrict__ eps,
                             __half2* __restrict__ c, int N,
                             float* __restrict__ out, int out_size) {
    if (blockIdx.x == gridDim.x - 1) {
        for (int i = threadIdx.x; i < out_size; i += blockDim.x) out[i] = 0.0f;
        return;
    }
    int n = blockIdx.x * blockDim.x + threadIdx.x;
    if (n >= N) return;
    float m  = mu[n];
    float sg = __expf(ls[n]);
    float v[8];
#pragma unroll
    for (int s = 0; s < 8; ++s) v[s] = m + sg * eps[(size_t)s * N + n];
    __half2* dst = c + (size_t)n * 4;
#pragma unroll
    for (int s = 0; s < 4; ++s) dst[s] = __floats2half2_rn(v[2 * s], v[2 * s + 1]);
}

// ---------------- edge kernel: R3 structure, nontemporal edge-stream loads
__global__ void __launch_bounds__(256, 8)
edge_loglik_s8(const i32x4* __restrict__ ep, const u32x4* __restrict__ c,
               float* __restrict__ out, long long E, float neg_inv_s) {
    long long tid    = (long long)blockIdx.x * blockDim.x + threadIdx.x;
    long long stride = (long long)gridDim.x * blockDim.x;
    float acc = 0.0f;
    long long P = E >> 1;                    // edge-pairs (4 ints each)

    for (long long q = tid; q < P; q += 2 * stride) {
        long long q1 = q + stride;
        bool has1 = q1 < P;
        i32x4 e0 = __builtin_nontemporal_load(ep + q);        // stream: L2 no-alloc
        i32x4 e1 = has1 ? __builtin_nontemporal_load(ep + q1) : e0;
        // table gathers: normal caching (L2-resident table)
        u32x4 a0 = c[e0.x], b0 = c[e0.y], d0 = c[e0.z], f0 = c[e0.w];
        u32x4 a1 = c[e1.x], b1 = c[e1.y], d1 = c[e1.z], f1 = c[e1.w];
        float s = edge_term(a0, b0) + edge_term(d0, f0);
        if (has1) s += edge_term(a1, b1) + edge_term(d1, f1);
        acc += s;
    }
    if ((E & 1) && tid == 0) {
        const int2* el = (const int2*)ep;
        int2 ij = el[E - 1];
        acc += edge_term(c[ij.x], c[ij.y]);
    }

    // wave (64-lane) reduction -> one atomic per block
#pragma unroll
    for (int off = 32; off > 0; off >>= 1) acc += __shfl_down(acc, off, 64);
    __shared__ float wsum[4];
    int lane = threadIdx.x & 63;
    int wid  = threadIdx.x >> 6;
    if (lane == 0) wsum[wid] = acc;
    __syncthreads();
    if (threadIdx.x == 0) {
        float s = 0.0f;
        for (int w = 0; w < (int)(blockDim.x >> 6); ++w) s += wsum[w];
        atomicAdd(out, s * neg_inv_s);
    }
}

// ---------------- generic-S fallback (harness uses S=8; kept for safety)
__global__ void compute_c_gen(const float* __restrict__ mu, const float* __restrict__ ls,
                              const float* __restrict__ eps, __half* __restrict__ c,
                              int N, int S, float* __restrict__ out, int out_size) {
    if (blockIdx.x == gridDim.x - 1) {
        for (int i = threadIdx.x; i < out_size; i += blockDim.x) out[i] = 0.0f;
        return;
    }
    int n = blockIdx.x * blockDim.x + threadIdx.x;
    if (n >= N) return;
    float m = mu[n], sg = __expf(ls[n]);
    for (int s = 0; s < S; ++s) c[(size_t)n * S + s] = __float2half(m + sg * eps[(size_t)s * N + n]);
}
__global__ void edge_loglik_gen(const int* __restrict__ ed, const __half* __restrict__ c,
                                float* __restrict__ out, long long E, int S, float neg_inv_s) {
    long long tid = (long long)blockIdx.x * blockDim.x + threadIdx.x;
    long long stride = (long long)gridDim.x * blockDim.x;
    float acc = 0.0f;
    for (long long e = tid; e < E; e += stride) {
        long long i = ed[2 * e], j = ed[2 * e + 1];
        for (int s = 0; s < S; ++s) {
            float x = __half2float(c[i * S + s]) * __half2float(c[j * S + s]);
            acc += __logf(1.0f + fminf(__expf(-x), 1.0e8f));
        }
    }
#pragma unroll
    for (int off = 32; off > 0; off >>= 1) acc += __shfl_down(acc, off, 64);
    __shared__ float wsum[8];
    int lane = threadIdx.x & 63, wid = threadIdx.x >> 6;
    if (lane == 0) wsum[wid] = acc;
    __syncthreads();
    if (threadIdx.x == 0) {
        float s = 0.0f;
        for (int w = 0; w < (int)(blockDim.x >> 6); ++w) s += wsum[w];
        atomicAdd(out, s * neg_inv_s);
    }
}

extern "C" void kernel_launch(void* const* d_in, const int* in_sizes, int n_in,
                              void* d_out, int out_size, void* d_ws, size_t ws_size,
                              hipStream_t stream) {
    const float* mu  = (const float*)d_in[0];
    const float* ls  = (const float*)d_in[1];
    const float* eps = (const float*)d_in[2];
    const int* edges = (const int*)d_in[3];    // int32 pairs (confirmed R4/R5)

    int       N = in_sizes[0];
    int       S = in_sizes[2] / N;             // 8
    long long E = (long long)in_sizes[3] / 2;  // 3.2M

    __half* c  = (__half*)d_ws;
    float* out = (float*)d_out;
    size_t sz_c = (size_t)N * S * sizeof(__half);
    float neg_inv_s = -1.0f / (float)S;

    int cblocks = (N + 255) / 256 + 1;         // +1 block zeroes d_out

    if (S == 8 && ws_size >= sz_c) {
        compute_c_h8<<<cblocks, 256, 0, stream>>>(mu, ls, eps, (__half2*)c, N, out, out_size);
        edge_loglik_s8<<<2048, 256, 0, stream>>>((const i32x4*)edges, (const u32x4*)c,
                                                 out, E, neg_inv_s);
    } else {
        compute_c_gen<<<cblocks, 256, 0, stream>>>(mu, ls, eps, c, N, S, out, out_size);
        edge_loglik_gen<<<2048, 256, 0, stream>>>(edges, c, out, E, S, neg_inv_s);
    }
}